// Round 1
// 212.304 us; speedup vs baseline: 1.0892x; 1.0892x over previous
//
#include <hip/hip_runtime.h>
#include <math.h>

// Qwen3 MoE sparse block, MI355X/gfx950.
// Sizes fixed by the reference: T=2048 tokens, H=1024, E=16, I=512, top-4.
// R7: router merged into prep grid (reads wg[H][E] directly, no wgT dep);
//     build_lists_kernel eliminated via atomic list-build (order-free: every
//     hidden/dtmp row depends only on its own token, so list permutation is
//     value-identical); offsets eliminated via fixed [E][2048] expert slabs.
constexpr int TT = 2048;   // tokens
constexpr int HH = 1024;   // hidden
constexpr int EE = 16;     // experts
constexpr int II = 512;    // intermediate

typedef unsigned short u16;
typedef short s16x8 __attribute__((ext_vector_type(8)));   // 8 bf16 for MFMA A/B
typedef float f32x4 __attribute__((ext_vector_type(4)));   // MFMA C/D

__device__ __forceinline__ u16 f2bf(float f) {
  unsigned u = __float_as_uint(f);
  u = (u + 0x7fffu + ((u >> 16) & 1u)) >> 16;   // round-to-nearest-even
  return (u16)u;
}
__device__ __forceinline__ float bf2f(u16 b) {
  return __uint_as_float(((unsigned)b) << 16);
}

// async global->LDS, 16B per lane; lds base must be wave-uniform (HW adds lane*16)
__device__ __forceinline__ void gl2lds16(const void* g, void* l) {
  __builtin_amdgcn_global_load_lds(
      (const __attribute__((address_space(1))) unsigned*)g,
      (__attribute__((address_space(3))) unsigned*)l, 16, 0, 0);
}

// ---------------- prep mega-kernel: router + weight transpose v4 + cast x ----------------
// bid [0,512):        router — 1 wave/token, logits from wg[H][E] directly, top-4,
//                     atomic list-build (counts strided 64B to dodge same-line atomics).
// bid [512,12800):    wtrans v4: tile 64n x 32k, lane owns 1n x 8k (R6 granule layout).
// bid [12800,14848):  cast x fp32 -> bf16.
__global__ __launch_bounds__(256) void prep_kernel(
    const float* __restrict__ wgp, const float* __restrict__ wup,
    const float* __restrict__ wdp, u16* __restrict__ wgt,
    u16* __restrict__ wut, u16* __restrict__ wdt,
    const float* __restrict__ x, u16* __restrict__ xb,
    const float* __restrict__ wg, float* __restrict__ rl,
    int* __restrict__ counts, int* __restrict__ tlist,
    float* __restrict__ wlist, int* __restrict__ rowof) {
  int bid = blockIdx.x;
  int tid = threadIdx.x;
  if (bid < 512) {
    // ---- router: one wave per token ----
    int lane = tid & 63, wv = tid >> 6;
    int t = bid * 4 + wv;
    const float* xr = x + (size_t)t * HH;
    float xv[16];
#pragma unroll
    for (int i = 0; i < 16; ++i) xv[i] = xr[lane + 64 * i];
    float lg[16];
#pragma unroll
    for (int e = 0; e < 16; ++e) lg[e] = 0.f;
#pragma unroll
    for (int i = 0; i < 16; ++i) {
      const float4* wr = reinterpret_cast<const float4*>(wg + (size_t)(lane + 64 * i) * EE);
      float4 w0 = wr[0], w1 = wr[1], w2 = wr[2], w3 = wr[3];
      float xs = xv[i];
      lg[0]  += xs * w0.x; lg[1]  += xs * w0.y; lg[2]  += xs * w0.z; lg[3]  += xs * w0.w;
      lg[4]  += xs * w1.x; lg[5]  += xs * w1.y; lg[6]  += xs * w1.z; lg[7]  += xs * w1.w;
      lg[8]  += xs * w2.x; lg[9]  += xs * w2.y; lg[10] += xs * w2.z; lg[11] += xs * w2.w;
      lg[12] += xs * w3.x; lg[13] += xs * w3.y; lg[14] += xs * w3.z; lg[15] += xs * w3.w;
    }
#pragma unroll
    for (int e = 0; e < 16; ++e) {
      float p = lg[e];
#pragma unroll
      for (int s = 32; s > 0; s >>= 1) p += __shfl_xor(p, s, 64);
      lg[e] = p;   // all lanes hold the full logit after butterfly
    }
    if (lane < 16) rl[(size_t)t * 16 + lane] = lg[lane];
    // top-4 (stable: earlier index wins ties, matches lax.top_k)
    unsigned mask = 0;
    int sel[4]; float bl[4];
#pragma unroll
    for (int k = 0; k < 4; ++k) {
      float best = -3.4e38f; int bi = 0;
#pragma unroll
      for (int e = 0; e < 16; ++e) {
        bool ok = !((mask >> e) & 1u) && (lg[e] > best);
        best = ok ? lg[e] : best;
        bi = ok ? e : bi;
      }
      mask |= 1u << bi;
      sel[k] = bi; bl[k] = best;
    }
    // normalized top-k softmax: full denominator cancels
    float mx = bl[0];
    float wk[4]; float s = 0.f;
#pragma unroll
    for (int k = 0; k < 4; ++k) { wk[k] = expf(bl[k] - mx); s += wk[k]; }
    float inv = 1.f / s;
    if (lane == 0) {
#pragma unroll
      for (int k = 0; k < 4; ++k) {
        int e = sel[k];
        int pos = atomicAdd(&counts[e * 16], 1);   // 64B-strided counters
        tlist[e * TT + pos] = t;
        wlist[e * TT + pos] = wk[k] * inv;
        rowof[t * 4 + k] = e * TT + pos;           // global slab row
      }
    }
  } else if (bid < 512 + 12288) {
    // ---- weight transpose: 48 regions x 256 blocks ----
    int b = bid - 512;
    int z = b >> 8, lb = b & 255;
    int e = z & 15, t = z >> 4;
    const float* src; u16* dst; int K, N;
    if (t == 0)      { src = wgp + (size_t)e * HH * II; dst = wgt + (size_t)e * II * HH; K = HH; N = II; }
    else if (t == 1) { src = wup + (size_t)e * HH * II; dst = wut + (size_t)e * II * HH; K = HH; N = II; }
    else             { src = wdp + (size_t)e * II * HH; dst = wdt + (size_t)e * HH * II; K = II; N = HH; }
    int nTiles = N >> 6;                 // 64-wide n tiles
    int n0 = (lb % nTiles) * 64;
    int k0 = (lb / nTiles) * 32;         // 32-deep k tiles
    int l = tid & 63, w = tid >> 6;
    int n  = n0 + w * 16 + (l >> 2);     // 1 n per thread
    int kc = l & 3;                      // k-chunk: 8 consecutive k
    float v[8];
#pragma unroll
    for (int j = 0; j < 8; ++j)
      v[j] = src[(size_t)(k0 + kc * 8 + j) * N + n];
    uint4 st;
    st.x = (unsigned)f2bf(v[0]) | ((unsigned)f2bf(v[1]) << 16);
    st.y = (unsigned)f2bf(v[2]) | ((unsigned)f2bf(v[3]) << 16);
    st.z = (unsigned)f2bf(v[4]) | ((unsigned)f2bf(v[5]) << 16);
    st.w = (unsigned)f2bf(v[6]) | ((unsigned)f2bf(v[7]) << 16);
    *reinterpret_cast<uint4*>(&dst[(size_t)n * K + k0 + kc * 8]) = st;
  } else {
    // ---- cast x fp32 -> bf16 ----
    int i = (bid - 12800) * 256 + tid;
    float4 v = reinterpret_cast<const float4*>(x)[i];
    ushort4 o;
    o.x = f2bf(v.x); o.y = f2bf(v.y); o.z = f2bf(v.z); o.w = f2bf(v.w);
    reinterpret_cast<ushort4*>(xb)[i] = o;
  }
}

// ---------------- gate+up fused GEMM -> hidden (bf16, pre-scaled by routing weight) ----------------
// R4: tile 128(M)x64(N), BK=64, swizzled LDS. 4 waves 2x2: wave = 64 rows x 32 cols.
// R7: fixed expert slabs — hidden row = e*2048 + mi; counts strided 16 ints.
__global__ __launch_bounds__(256, 2) void gateup_kernel(
    const u16* __restrict__ xb, const u16* __restrict__ wgt, const u16* __restrict__ wut,
    const int* __restrict__ counts,
    const int* __restrict__ tlist, const float* __restrict__ wlist,
    u16* __restrict__ hidden) {
  int e = blockIdx.z, mt = blockIdx.y, nt = blockIdx.x;   // nt 0..7 (64 cols each)
  int cnt = counts[e * 16];
  if (mt * 128 >= cnt) return;
  __shared__ u16 As[128 * 64];   // [m][k] swizzled
  __shared__ u16 Bg[64 * 64];    // [n][k] swizzled
  __shared__ u16 Bu[64 * 64];
  int tid = threadIdx.x, lane = tid & 63, wv = tid >> 6;
  int wm = wv >> 1, wn = wv & 1;
  int srow = lane >> 3;                     // staging row within 8-row chunk
  int scol = (((lane & 7) ^ srow)) * 8;     // swizzled global k-offset (u16)
  const u16* wgE = wgt + (size_t)e * II * HH;
  const u16* wuE = wut + (size_t)e * II * HH;
  const u16* gp[8];
#pragma unroll
  for (int c = 0; c < 8; ++c) {
    int chunk = c * 4 + wv;
    const u16* p;
    if (chunk < 16) {
      int mi = mt * 128 + chunk * 8 + srow; if (mi >= cnt) mi = cnt - 1;
      int tok = tlist[e * TT + mi];
      p = xb + (size_t)tok * HH + scol;
    } else if (chunk < 24) {
      int n = nt * 64 + (chunk - 16) * 8 + srow;
      p = wgE + (size_t)n * HH + scol;
    } else {
      int n = nt * 64 + (chunk - 24) * 8 + srow;
      p = wuE + (size_t)n * HH + scol;
    }
    gp[c] = p;
  }
  f32x4 accG[4][2] = {}; f32x4 accU[4][2] = {};
  int quad = lane >> 4, colc = lane & 15;
  for (int k0 = 0; k0 < HH; k0 += 64) {
#pragma unroll
    for (int c = 0; c < 8; ++c) {
      int chunk = c * 4 + wv;
      u16* dst = (chunk < 16) ? &As[chunk * 512]
               : (chunk < 24) ? &Bg[(chunk - 16) * 512]
                              : &Bu[(chunk - 24) * 512];
      gl2lds16(gp[c] + k0, dst);
    }
    __syncthreads();
#pragma unroll
    for (int kk = 0; kk < 64; kk += 32) {
      int gl = (kk >> 3) + quad;            // logical k-group
      s16x8 a[4], bg[2], bu[2];
#pragma unroll
      for (int f = 0; f < 4; ++f) {
        int m = wm * 64 + f * 16 + colc;
        a[f] = *reinterpret_cast<const s16x8*>(&As[m * 64 + ((gl ^ (m & 7)) << 3)]);
      }
#pragma unroll
      for (int f = 0; f < 2; ++f) {
        int n = wn * 32 + f * 16 + colc;
        bg[f] = *reinterpret_cast<const s16x8*>(&Bg[n * 64 + ((gl ^ (n & 7)) << 3)]);
        bu[f] = *reinterpret_cast<const s16x8*>(&Bu[n * 64 + ((gl ^ (n & 7)) << 3)]);
      }
#pragma unroll
      for (int fm = 0; fm < 4; ++fm)
#pragma unroll
        for (int fn = 0; fn < 2; ++fn) {
          accG[fm][fn] = __builtin_amdgcn_mfma_f32_16x16x32_bf16(a[fm], bg[fn], accG[fm][fn], 0, 0, 0);
          accU[fm][fn] = __builtin_amdgcn_mfma_f32_16x16x32_bf16(a[fm], bu[fn], accU[fm][fn], 0, 0, 0);
        }
    }
    __syncthreads();
  }
  // epilogue: hidden = w_route * silu(g) * u   (C/D: col=lane&15, row=quad*4+reg)
  int hb = e * TT;
#pragma unroll
  for (int fm = 0; fm < 4; ++fm) {
#pragma unroll
    for (int r = 0; r < 4; ++r) {
      int mi = mt * 128 + wm * 64 + fm * 16 + quad * 4 + r;
      if (mi < cnt) {
        float wr = wlist[e * TT + mi];
        u16* hrow = hidden + (size_t)(hb + mi) * II + nt * 64 + wn * 32;
#pragma unroll
        for (int fn = 0; fn < 2; ++fn) {
          float g = accG[fm][fn][r], u = accU[fm][fn][r];
          float hval = wr * u * g / (1.f + expf(-g));
          hrow[fn * 16 + colc] = f2bf(hval);
        }
      }
    }
  }
}

// ---------------- down GEMM: hidden @ wd^T -> dense bf16 rows in dtmp (no atomics) ----------------
// Rows past cnt in the expert slab hold workspace poison; they feed only MFMA output
// rows that are discarded (each output row depends only on its own A row).
__global__ __launch_bounds__(256, 2) void down_kernel(
    const u16* __restrict__ hidden, const u16* __restrict__ wdt,
    const int* __restrict__ counts,
    u16* __restrict__ dtmp) {
  int e = blockIdx.z, mt = blockIdx.y, nt = blockIdx.x;
  int cnt = counts[e * 16];
  if (mt * 128 >= cnt) return;
  int hb = e * TT;
  __shared__ u16 As[128 * 64];
  __shared__ u16 Bs[128 * 64];
  int tid = threadIdx.x, lane = tid & 63, wv = tid >> 6;
  int wm = wv >> 1, wn = wv & 1;
  int srow = lane >> 3;
  int scol = (((lane & 7) ^ srow)) * 8;     // swizzled global k-offset
  const u16* wdE = wdt + (size_t)e * HH * II;
  const u16* gA[4]; const u16* gB[4];
#pragma unroll
  for (int c = 0; c < 4; ++c) {
    int chunk = c * 4 + wv;
    int row = hb + mt * 128 + chunk * 8 + srow;   // always inside [E*TT] slab buffer
    gA[c] = hidden + (size_t)row * II + scol;
    int n = nt * 128 + chunk * 8 + srow;
    gB[c] = wdE + (size_t)n * II + scol;
  }
  f32x4 acc[4][4] = {};
  int quad = lane >> 4, colc = lane & 15;
  for (int k0 = 0; k0 < II; k0 += 64) {
#pragma unroll
    for (int c = 0; c < 4; ++c) {
      int chunk = c * 4 + wv;
      gl2lds16(gA[c] + k0, &As[chunk * 512]);
      gl2lds16(gB[c] + k0, &Bs[chunk * 512]);
    }
    __syncthreads();
#pragma unroll
    for (int kk = 0; kk < 64; kk += 32) {
      int gl = (kk >> 3) + quad;
      s16x8 a[4], b[4];
#pragma unroll
      for (int f = 0; f < 4; ++f) {
        int m = wm * 64 + f * 16 + colc;
        int n = wn * 64 + f * 16 + colc;
        a[f] = *reinterpret_cast<const s16x8*>(&As[m * 64 + ((gl ^ (m & 7)) << 3)]);
        b[f] = *reinterpret_cast<const s16x8*>(&Bs[n * 64 + ((gl ^ (n & 7)) << 3)]);
      }
#pragma unroll
      for (int fm = 0; fm < 4; ++fm)
#pragma unroll
        for (int fn = 0; fn < 4; ++fn)
          acc[fm][fn] = __builtin_amdgcn_mfma_f32_16x16x32_bf16(a[fm], b[fn], acc[fm][fn], 0, 0, 0);
    }
    __syncthreads();
  }
#pragma unroll
  for (int fm = 0; fm < 4; ++fm) {
#pragma unroll
    for (int r = 0; r < 4; ++r) {
      int mi = mt * 128 + wm * 64 + fm * 16 + quad * 4 + r;
      if (mi < cnt) {
        u16* drow = dtmp + (size_t)(hb + mi) * HH + nt * 128 + wn * 64;
#pragma unroll
        for (int fn = 0; fn < 4; ++fn)
          drow[fn * 16 + colc] = f2bf(acc[fm][fn][r]);
      }
    }
  }
}

// ---------------- combine: out[t] = sum of 4 expert rows (routing weight already applied) ----------------
__global__ void combine_kernel(const u16* __restrict__ dtmp, const int* __restrict__ rowof,
                               float* __restrict__ out) {
  int t = blockIdx.x, tid = threadIdx.x;
  int4 rw = reinterpret_cast<const int4*>(rowof)[t];
  int h = tid * 4;
  float s0 = 0.f, s1 = 0.f, s2 = 0.f, s3 = 0.f;
  int rows[4] = {rw.x, rw.y, rw.z, rw.w};
#pragma unroll
  for (int k = 0; k < 4; ++k) {
    ushort4 v = *reinterpret_cast<const ushort4*>(&dtmp[(size_t)rows[k] * HH + h]);
    s0 += bf2f(v.x); s1 += bf2f(v.y); s2 += bf2f(v.z); s3 += bf2f(v.w);
  }
  *reinterpret_cast<float4*>(&out[(size_t)t * HH + h]) = make_float4(s0, s1, s2, s3);
}

extern "C" void kernel_launch(void* const* d_in, const int* in_sizes, int n_in,
                              void* d_out, int out_size, void* d_ws, size_t ws_size,
                              hipStream_t stream) {
  const float* x   = (const float*)d_in[0];   // [1,2048,1024]
  const float* wg  = (const float*)d_in[1];   // [1024,16]
  const float* wgp = (const float*)d_in[2];   // [16,1024,512]
  const float* wup = (const float*)d_in[3];   // [16,1024,512]
  const float* wdp = (const float*)d_in[4];   // [16,512,1024]
  float* out = (float*)d_out;                 // [2048*1024] then router_logits [2048*16]
  float* rl  = out + (size_t)TT * HH;

  constexpr size_t MB = 1048576;
  char* w = (char*)d_ws;
  int*      counts  = (int*)(w + 0);                  // 16 counters, 64B-strided (1 KB)
  int*      rowof   = (int*)(w + 4096);               // [T][4] slab row ids (32 KB)
  int*      tlist   = (int*)(w + 65536);              // [E][T] token ids (128 KB)
  float*    wlist   = (float*)(w + 65536 + 131072);   // [E][T] routing weights (128 KB)
  u16*      xb      = (u16*)(w + 1 * MB);             // [T][H] bf16 (4 MB)
  u16*      wgt     = (u16*)(w + 8 * MB);             // [E][I][H] bf16 (16 MB)
  u16*      wut     = (u16*)(w + 24 * MB);            // 16 MB
  u16*      wdt     = (u16*)(w + 40 * MB);            // [E][H][I] bf16 (16 MB)
  u16*      hidden  = (u16*)(w + 56 * MB);            // [E*T][I] bf16 slabs (32 MB)
  u16*      dtmp    = (u16*)(w + 96 * MB);            // [E*T][H] bf16 slabs (64 MB)

  hipMemsetAsync(counts, 0, 1024, stream);
  hipLaunchKernelGGL(prep_kernel, dim3(512 + 12288 + 2048), dim3(256), 0, stream,
                     wgp, wup, wdp, wgt, wut, wdt, x, xb, wg, rl,
                     counts, tlist, wlist, rowof);
  hipLaunchKernelGGL(gateup_kernel, dim3(8, 16, 16), dim3(256), 0, stream,
                     xb, wgt, wut, counts, tlist, wlist, hidden);
  hipLaunchKernelGGL(down_kernel, dim3(8, 16, 16), dim3(256), 0, stream,
                     hidden, wdt, counts, dtmp);
  hipLaunchKernelGGL(combine_kernel, dim3(TT), dim3(256), 0, stream,
                     dtmp, rowof, out);
}